// Round 5
// baseline (424.763 us; speedup 1.0000x reference)
//
#include <hip/hip_runtime.h>

// ---------------------------------------------------------------------------
// EncoderLayer: x -> MHA(entmax1.5) -> +LN -> FFN(mish) -> +LN
// B=8 S=1024 D=512 H=8 hd=64 F=2048.  bf16 MFMA GEMMs, fp32 accum/epilogues.
// Round 5: entmax via closed-form support iteration (reference formula,
// ~4 iters, register-resident, barrier-free), chunk-pair staging in fused
// attention (half the barriers), split-K for the N=512 GEMMs (Wo x2, W2 x4)
// with partial-sum + bias folded into ln_res.
// ---------------------------------------------------------------------------

typedef float f32x4 __attribute__((ext_vector_type(4)));
typedef __bf16 b8 __attribute__((ext_vector_type(8)));

#define DEV static __device__ __forceinline__

DEV unsigned short f2bf(float f) {
  unsigned u = __float_as_uint(f);
  u += 0x7fffu + ((u >> 16) & 1u);   // RNE
  return (unsigned short)(u >> 16);
}
DEV float bf2f(unsigned short b) { return __uint_as_float(((unsigned)b) << 16); }

DEV float mishf(float x) {
  if (x > 20.f) return x;
  float e = __expf(x);
  float u = 1.f + e;
  u *= u;
  return x * ((u - 1.f) / (u + 1.f));
}

DEV void async16(const void* g, void* l) {
  __builtin_amdgcn_global_load_lds(
      (const __attribute__((address_space(1))) unsigned int*)g,
      (__attribute__((address_space(3))) unsigned int*)l, 16, 0, 0);
}

// ---------------------------------------------------------------------------
// Generic MFMA GEMM:  C[M,N] = alpha * A[M,K] * Bt[N,K]^T (+bias) (+mish)
// Batched / split-K via blockIdx.z: off = (z/hdiv)*s1 + (z%hdiv)*s2.
// (verified since round 2)
// ---------------------------------------------------------------------------
template <int WM, int WN, int EPI, bool OUTBF>
__global__ __launch_bounds__(256) void gemm_bt(
    const unsigned short* __restrict__ A, const unsigned short* __restrict__ Bt,
    const float* __restrict__ bias, void* __restrict__ Cp,
    int K, int lda, int ldb, int ldc,
    long sA1, long sA2, long sB1, long sB2, long sC1, long sC2,
    int hdiv, float alpha) {
  constexpr int BM = WM * 64, BN = WN * 64;
  __shared__ unsigned short smA[BM * 32];
  __shared__ unsigned short smB[BN * 32];

  const int tid = threadIdx.x;
  const int lane = tid & 63;
  const int z = blockIdx.z;
  const long zi = z / hdiv, zr = z % hdiv;
  const unsigned short* Ab = A + zi * sA1 + zr * sA2 + (long)blockIdx.x * BM * lda;
  const unsigned short* Bb = Bt + zi * sB1 + zr * sB2 + (long)blockIdx.y * BN * ldb;

  int siA[WM];
  const unsigned short* gA[WM];
#pragma unroll
  for (int q = 0; q < WM; ++q) {
    int si = q * 256 + tid;
    int m = si >> 2, s = si & 3, g = s ^ ((m >> 1) & 3);
    siA[q] = si;
    gA[q] = Ab + (long)m * lda + g * 8;
  }
  int siB[WN];
  const unsigned short* gB[WN];
#pragma unroll
  for (int q = 0; q < WN; ++q) {
    int si = q * 256 + tid;
    int m = si >> 2, s = si & 3, g = s ^ ((m >> 1) & 3);
    siB[q] = si;
    gB[q] = Bb + (long)m * ldb + g * 8;
  }

  const int w = tid >> 6;
  const int wr = w / WN, wc = w % WN;
  const int fm = lane & 15, fg = lane >> 4;

  int aOff[4], bOff[4];
#pragma unroll
  for (int i = 0; i < 4; ++i) {
    int m = wr * 64 + i * 16 + fm;
    aOff[i] = (m * 4 + (fg ^ ((m >> 1) & 3))) * 8;
    int n = wc * 64 + i * 16 + fm;
    bOff[i] = (n * 4 + (fg ^ ((n >> 1) & 3))) * 8;
  }

  f32x4 acc[4][4];
#pragma unroll
  for (int i = 0; i < 4; ++i)
#pragma unroll
    for (int j = 0; j < 4; ++j) acc[i][j] = (f32x4){0.f, 0.f, 0.f, 0.f};

  for (int k0 = 0; k0 < K; k0 += 32) {
    __syncthreads();
#pragma unroll
    for (int q = 0; q < WM; ++q) async16(gA[q] + k0, (void*)&smA[siA[q] * 8]);
#pragma unroll
    for (int q = 0; q < WN; ++q) async16(gB[q] + k0, (void*)&smB[siB[q] * 8]);
    __syncthreads();

    b8 aF[4], bF[4];
#pragma unroll
    for (int i = 0; i < 4; ++i) aF[i] = *(const b8*)&smA[aOff[i]];
#pragma unroll
    for (int j = 0; j < 4; ++j) bF[j] = *(const b8*)&smB[bOff[j]];
#pragma unroll
    for (int i = 0; i < 4; ++i)
#pragma unroll
      for (int j = 0; j < 4; ++j)
        acc[i][j] = __builtin_amdgcn_mfma_f32_16x16x32_bf16(aF[i], bF[j], acc[i][j], 0, 0, 0);
  }

  const long cbase = zi * sC1 + zr * sC2;
  const int row0 = blockIdx.x * BM + wr * 64 + fg * 4;
  const int col0 = blockIdx.y * BN + wc * 64 + fm;
#pragma unroll
  for (int i = 0; i < 4; ++i) {
#pragma unroll
    for (int j = 0; j < 4; ++j) {
      const int col = col0 + j * 16;
      float bv = (EPI >= 1) ? bias[col] : 0.f;
#pragma unroll
      for (int r = 0; r < 4; ++r) {
        const int row = row0 + i * 16 + r;
        float v = acc[i][j][r] * alpha + bv;
        if (EPI == 2) v = mishf(v);
        const long idx = cbase + (long)row * ldc + col;
        if constexpr (OUTBF)
          ((unsigned short*)Cp)[idx] = f2bf(v);
        else
          ((float*)Cp)[idx] = v;
      }
    }
  }
}

// ---------------------------------------------------------------------------
// Fused attention, one block = one (b,h) x 16 Q-rows. QKV packed [8192][1536].
//   phase A: z = (Q K^T)/16 -> bf16 LDS strip [16][1032], 2 chunks/barrier
//   phase B: entmax-1.5, register-resident closed-form support iteration
//   phase C: O = P @ V, 2 chunks/barrier
// LDS 51.5 KB -> 3 blocks/CU.
// ---------------------------------------------------------------------------
__global__ __launch_bounds__(256, 3) void fused_attn(
    const unsigned short* __restrict__ QKV, const unsigned short* __restrict__ Vt,
    unsigned short* __restrict__ Og) {
  constexpr int LDP = 1032;
  __shared__ unsigned short sP[16 * LDP];     // 33024 B
  __shared__ unsigned short sQ[16 * 64];      // 2048 B
  __shared__ unsigned short sKV[2 * 64 * 64]; // 16384 B (two 64-row halves)

  const int tid = threadIdx.x, lane = tid & 63, wv = tid >> 6;
  const int fm = lane & 15, fg = lane >> 4;
  const int qt = blockIdx.x, bh = blockIdx.y;
  const int b = bh >> 3, h = bh & 7;
  const long qkBase = (long)b * 1024 * 1536 + h * 64;
  const long vtBase = (long)bh * 64 * 1024;

  // stage Q tile (16x64): 128 slots of 16 B (waves 0-1)
  if (tid < 128) {
    const unsigned short* Qp = QKV + qkBase + (long)qt * 16 * 1536;
    int m = tid >> 3, s = tid & 7;
    async16(Qp + m * 1536 + s * 8, &sQ[tid * 8]);
  }

  // 64-row chunk slot descriptors (swizzle: slot s holds global group s^(m&7))
  int mK[2], gK[2];
#pragma unroll
  for (int q = 0; q < 2; ++q) {
    int si = q * 256 + tid;
    mK[q] = si >> 3;
    gK[q] = (si & 7) ^ (mK[q] & 7);
  }

  b8 aQ[2];
  const int n = wv * 16 + fm;
  int bOffK[2];
#pragma unroll
  for (int k = 0; k < 2; ++k) bOffK[k] = n * 64 + ((k * 4 + fg) ^ (n & 7)) * 8;

  // ---------------- phase A: 8 chunk-pairs ----------------
  const unsigned short* Kp = QKV + qkBase + 512;
  for (int c = 0; c < 8; ++c) {
    __syncthreads();
#pragma unroll
    for (int hh = 0; hh < 2; ++hh)
#pragma unroll
      for (int q = 0; q < 2; ++q)
        async16(Kp + (long)((c * 2 + hh) * 64 + mK[q]) * 1536 + gK[q] * 8,
                &sKV[hh * 4096 + (q * 256 + tid) * 8]);
    __syncthreads();  // vmcnt(0): staging complete (drains Q stage at c==0)

    if (c == 0) {
#pragma unroll
      for (int k = 0; k < 2; ++k)
        aQ[k] = *(const b8*)&sQ[fm * 64 + k * 32 + fg * 8];
    }

#pragma unroll
    for (int hh = 0; hh < 2; ++hh) {
      b8 bK[2];
#pragma unroll
      for (int k = 0; k < 2; ++k) bK[k] = *(const b8*)&sKV[hh * 4096 + bOffK[k]];
      f32x4 a0 = (f32x4){0.f, 0.f, 0.f, 0.f};
#pragma unroll
      for (int k = 0; k < 2; ++k)
        a0 = __builtin_amdgcn_mfma_f32_16x16x32_bf16(aQ[k], bK[k], a0, 0, 0, 0);
      const int col = (c * 2 + hh) * 64 + wv * 16 + fm;
#pragma unroll
      for (int r = 0; r < 4; ++r)
        sP[(fg * 4 + r) * LDP + col] = f2bf(a0[r] * (1.f / 16.f));
    }
  }
  __syncthreads();  // strip complete

  // ---------------- phase B: entmax, wave owns rows wv*4..wv*4+3 -----------
  // Support iteration (reference closed form): tau' = tau + (s1-sqrt(s1^2 -
  // k(s2-1)))/k over support {z>tau}; support shrinks monotonically from
  // {z > max-1}; exact when k repeats. disc clamp == reference's delta clip.
  {
    float zv[4][16];
    float tau[4];
    int kprev[4];
    unsigned short* pr[4];
    union { uint4 v; unsigned short u[8]; } t[8];
#pragma unroll
    for (int r = 0; r < 4; ++r) {
      pr[r] = &sP[(wv * 4 + r) * LDP];
      t[2 * r].v = *(const uint4*)(pr[r] + lane * 8);
      t[2 * r + 1].v = *(const uint4*)(pr[r] + 512 + lane * 8);
#pragma unroll
      for (int i = 0; i < 8; ++i) {
        zv[r][i] = bf2f(t[2 * r].u[i]);
        zv[r][8 + i] = bf2f(t[2 * r + 1].u[i]);
      }
    }
#pragma unroll
    for (int r = 0; r < 4; ++r) {
      float m = zv[r][0];
#pragma unroll
      for (int i = 1; i < 16; ++i) m = fmaxf(m, zv[r][i]);
#pragma unroll
      for (int o = 32; o; o >>= 1) m = fmaxf(m, __shfl_xor(m, o));
#pragma unroll
      for (int i = 0; i < 16; ++i) zv[r][i] -= m;
      tau[r] = -1.f;
      kprev[r] = -1;
    }
    for (int it = 0; it < 10; ++it) {
      float s1[4], s2[4];
      int k[4];
#pragma unroll
      for (int r = 0; r < 4; ++r) {
        s1[r] = 0.f;
        s2[r] = 0.f;
        k[r] = 0;
#pragma unroll
        for (int i = 0; i < 16; ++i) {
          float hh = zv[r][i] - tau[r];
          k[r] += __popcll(__ballot(hh > 0.f));
          float hp = fmaxf(hh, 0.f);
          s1[r] += hp;
          s2[r] = fmaf(hp, hp, s2[r]);
        }
      }
#pragma unroll
      for (int o = 32; o; o >>= 1)
#pragma unroll
        for (int r = 0; r < 4; ++r) {
          s1[r] += __shfl_xor(s1[r], o);
          s2[r] += __shfl_xor(s2[r], o);
        }
      bool conv = true;  // wave-uniform: k from ballot, s from full reduction
#pragma unroll
      for (int r = 0; r < 4; ++r) {
        if (k[r] != kprev[r]) {
          conv = false;
          kprev[r] = k[r];
          float kf = (float)k[r];
          float disc = fmaxf(fmaf(s1[r], s1[r], -kf * (s2[r] - 1.f)), 0.f);
          tau[r] += (s1[r] - __builtin_sqrtf(disc)) / kf;
        }
      }
      if (conv) break;
    }
#pragma unroll
    for (int r = 0; r < 4; ++r) {
#pragma unroll
      for (int i = 0; i < 8; ++i) {
        float h0 = fmaxf(zv[r][i] - tau[r], 0.f);
        float h1 = fmaxf(zv[r][8 + i] - tau[r], 0.f);
        t[2 * r].u[i] = f2bf(h0 * h0);
        t[2 * r + 1].u[i] = f2bf(h1 * h1);
      }
      *(uint4*)(pr[r] + lane * 8) = t[2 * r].v;
      *(uint4*)(pr[r] + 512 + lane * 8) = t[2 * r + 1].v;
    }
  }

  // ---------------- phase C: O = P @ V, 8 chunk-pairs ----------------
  f32x4 o0 = (f32x4){0.f, 0.f, 0.f, 0.f};
  for (int c = 0; c < 8; ++c) {
    __syncthreads();  // c==0: all waves' phase-B writes done
#pragma unroll
    for (int hh = 0; hh < 2; ++hh)
#pragma unroll
      for (int q = 0; q < 2; ++q)
        async16(Vt + vtBase + (long)mK[q] * 1024 + (c * 2 + hh) * 64 + gK[q] * 8,
                &sKV[hh * 4096 + (q * 256 + tid) * 8]);
    __syncthreads();

#pragma unroll
    for (int hh = 0; hh < 2; ++hh) {
      b8 bV[2];
#pragma unroll
      for (int k = 0; k < 2; ++k) bV[k] = *(const b8*)&sKV[hh * 4096 + bOffK[k]];
#pragma unroll
      for (int k = 0; k < 2; ++k) {
        b8 aP = *(const b8*)&sP[fm * LDP + (c * 2 + hh) * 64 + k * 32 + fg * 8];
        o0 = __builtin_amdgcn_mfma_f32_16x16x32_bf16(aP, bV[k], o0, 0, 0, 0);
      }
    }
  }

  const long orow0 = (long)b * 1024 + qt * 16;
  const int colg = h * 64 + wv * 16 + fm;
#pragma unroll
  for (int r = 0; r < 4; ++r)
    Og[(orow0 + fg * 4 + r) * 512 + colg] = f2bf(o0[r]);
}

// ---------------------------------------------------------------------------
__global__ __launch_bounds__(256) void cast_f2b(const float* __restrict__ in,
                                                unsigned short* __restrict__ out, long n) {
  long i = ((long)blockIdx.x * 256 + threadIdx.x) * 4;
  if (i >= n) return;
  float4 v = *(const float4*)&in[i];
  unsigned lo = (unsigned)f2bf(v.x) | ((unsigned)f2bf(v.y) << 16);
  unsigned hi = (unsigned)f2bf(v.z) | ((unsigned)f2bf(v.w) << 16);
  uint2 p;
  p.x = lo;
  p.y = hi;
  *(uint2*)&out[i] = p;
}

__global__ __launch_bounds__(256) void concat3(const float* __restrict__ a,
                                               const float* __restrict__ b,
                                               const float* __restrict__ c,
                                               float* __restrict__ o) {
  int i = blockIdx.x * 256 + threadIdx.x;
  if (i < 512) o[i] = a[i];
  else if (i < 1024) o[i] = b[i - 512];
  else if (i < 1536) o[i] = c[i - 1024];
}

__global__ __launch_bounds__(256) void transpose_f2b(const float* __restrict__ in,
                                                     unsigned short* __restrict__ out,
                                                     int ldi, int ldo) {
  __shared__ float t[32][33];
  const int tx = threadIdx.x & 31, ty = threadIdx.x >> 5;
  const int r0 = blockIdx.y * 32, c0 = blockIdx.x * 32;
#pragma unroll
  for (int q = 0; q < 4; ++q) {
    int r = ty + q * 8;
    t[r][tx] = in[(long)(r0 + r) * ldi + c0 + tx];
  }
  __syncthreads();
#pragma unroll
  for (int q = 0; q < 4; ++q) {
    int r = ty + q * 8;
    out[(long)(c0 + r) * ldo + r0 + tx] = f2bf(t[tx][r]);
  }
}

__global__ __launch_bounds__(256) void transpose_b2b(const unsigned short* __restrict__ in,
                                                     unsigned short* __restrict__ out,
                                                     int ldi, int ldo, long i1, long i2,
                                                     long o1, long o2, int hdiv) {
  __shared__ unsigned short t[32][33];
  const int z = blockIdx.z;
  in += (long)(z / hdiv) * i1 + (long)(z % hdiv) * i2;
  out += (long)(z / hdiv) * o1 + (long)(z % hdiv) * o2;
  const int tx = threadIdx.x & 31, ty = threadIdx.x >> 5;
  const int r0 = blockIdx.y * 32, c0 = blockIdx.x * 32;
#pragma unroll
  for (int q = 0; q < 4; ++q) {
    int r = ty + q * 8;
    t[r][tx] = in[(long)(r0 + r) * ldi + c0 + tx];
  }
  __syncthreads();
#pragma unroll
  for (int q = 0; q < 4; ++q) {
    int r = ty + q * 8;
    out[(long)(c0 + r) * ldo + r0 + tx] = t[tx][r];
  }
}

// ---------------------------------------------------------------------------
// out = xin + LayerNorm(sum_j y[j*ystr] + ybias)*g + be   (row 512)
// NS split-K partials summed here; ybias (bo/b2) added BEFORE LN stats.
// ---------------------------------------------------------------------------
template <bool WB, int NS>
__global__ __launch_bounds__(256) void ln_res(const float* __restrict__ xin,
                                              const float* __restrict__ y, long ystr,
                                              const float* __restrict__ ybias,
                                              const float* __restrict__ g,
                                              const float* __restrict__ be,
                                              float* __restrict__ xo,
                                              unsigned short* __restrict__ xob) {
  const int row = blockIdx.x, tid = threadIdx.x, lane = tid & 63, wv = tid >> 6;
  const long base = (long)row * 512 + tid * 2;
  const int c = tid * 2;
  float2 v = *(const float2*)&y[base];
#pragma unroll
  for (int j = 1; j < NS; ++j) {
    float2 u = *(const float2*)&y[base + j * ystr];
    v.x += u.x;
    v.y += u.y;
  }
  v.x += ybias[c];
  v.y += ybias[c + 1];
  float s1 = v.x + v.y, s2 = v.x * v.x + v.y * v.y;
  for (int o = 32; o; o >>= 1) {
    s1 += __shfl_xor(s1, o);
    s2 += __shfl_xor(s2, o);
  }
  __shared__ float red[4][2];
  if (lane == 0) {
    red[wv][0] = s1;
    red[wv][1] = s2;
  }
  __syncthreads();
  s1 = red[0][0] + red[1][0] + red[2][0] + red[3][0];
  s2 = red[0][1] + red[1][1] + red[2][1] + red[3][1];
  const float mu = s1 * (1.f / 512.f);
  const float rstd = rsqrtf(s2 * (1.f / 512.f) - mu * mu + 1e-5f);
  float2 xv = *(const float2*)&xin[base];
  float o0 = xv.x + (v.x - mu) * rstd * g[c] + be[c];
  float o1 = xv.y + (v.y - mu) * rstd * g[c + 1] + be[c + 1];
  float2 ov;
  ov.x = o0;
  ov.y = o1;
  *(float2*)&xo[base] = ov;
  if constexpr (WB) {
    unsigned pk = (unsigned)f2bf(o0) | ((unsigned)f2bf(o1) << 16);
    *(unsigned*)&xob[base] = pk;
  }
}

// ---------------------------------------------------------------------------
extern "C" void kernel_launch(void* const* d_in, const int* in_sizes, int n_in,
                              void* d_out, int out_size, void* d_ws, size_t ws_size,
                              hipStream_t stream) {
  const int B = 8, S = 1024, D = 512, F = 2048;
  const int BS = B * S;  // 8192 rows
  const int N3 = 3 * D;  // 1536

  const float* x = (const float*)d_in[0];
  const float* Wq = (const float*)d_in[1];
  const float* bq = (const float*)d_in[2];
  const float* Wk = (const float*)d_in[3];
  const float* bk = (const float*)d_in[4];
  const float* Wv = (const float*)d_in[5];
  const float* bv = (const float*)d_in[6];
  const float* Wo = (const float*)d_in[7];
  const float* bo = (const float*)d_in[8];
  const float* g1 = (const float*)d_in[9];
  const float* be1 = (const float*)d_in[10];
  const float* W1 = (const float*)d_in[11];
  const float* b1 = (const float*)d_in[12];
  const float* W2 = (const float*)d_in[13];
  const float* b2 = (const float*)d_in[14];
  const float* g2 = (const float*)d_in[15];
  const float* be2 = (const float*)d_in[16];
  float* out = (float*)d_out;

  char* w = (char*)d_ws;
  size_t off = 0;
  auto alloc = [&](size_t bytes) -> void* {
    void* p = w + off;
    off += bytes;
    off = (off + 255) & ~(size_t)255;
    return p;
  };

  unsigned short* xb = (unsigned short*)alloc((size_t)BS * D * 2);
  unsigned short* Wqkvt = (unsigned short*)alloc((size_t)N3 * D * 2);
  unsigned short* Wot = (unsigned short*)alloc((size_t)D * D * 2);
  unsigned short* W1t = (unsigned short*)alloc((size_t)F * D * 2);
  unsigned short* W2t = (unsigned short*)alloc((size_t)D * F * 2);
  float* bqkv = (float*)alloc((size_t)N3 * 4);
  unsigned short* QKVb = (unsigned short*)alloc((size_t)BS * N3 * 2);
  unsigned short* Vt = (unsigned short*)alloc((size_t)BS * D * 2);
  unsigned short* attn = (unsigned short*)alloc((size_t)BS * D * 2);
  float* yp = (float*)alloc((size_t)4 * BS * D * 4);  // split-K partials
  float* x1 = (float*)alloc((size_t)BS * D * 4);
  unsigned short* hb = (unsigned short*)alloc((size_t)BS * F * 2);
  unsigned short* x1b = xb;  // reuse: xb dead after QKV GEMM
  const long PSTR = (long)BS * D;

  // 1) casts + weight transposes (bf16, N x K form)
  cast_f2b<<<(BS * D) / 1024, 256, 0, stream>>>(x, xb, (long)BS * D);
  transpose_f2b<<<dim3(16, 16, 1), 256, 0, stream>>>(Wq, Wqkvt, D, D);
  transpose_f2b<<<dim3(16, 16, 1), 256, 0, stream>>>(Wk, Wqkvt + (size_t)D * D, D, D);
  transpose_f2b<<<dim3(16, 16, 1), 256, 0, stream>>>(Wv, Wqkvt + (size_t)2 * D * D, D, D);
  transpose_f2b<<<dim3(16, 16, 1), 256, 0, stream>>>(Wo, Wot, D, D);
  transpose_f2b<<<dim3(F / 32, D / 32, 1), 256, 0, stream>>>(W1, W1t, F, D);
  transpose_f2b<<<dim3(D / 32, F / 32, 1), 256, 0, stream>>>(W2, W2t, D, F);
  concat3<<<6, 256, 0, stream>>>(bq, bk, bv, bqkv);

  // 2) merged QKV projection: [8192][1536] bf16
  gemm_bt<2, 2, 1, true><<<dim3(BS / 128, N3 / 128, 1), 256, 0, stream>>>(
      xb, Wqkvt, bqkv, QKVb, D, D, D, N3, 0, 0, 0, 0, 0, 0, 1, 1.f);

  // 3) V -> Vt[(b,h), d, s]
  transpose_b2b<<<dim3(2, 32, 64), 256, 0, stream>>>(
      QKVb + 1024, Vt, N3, S, (long)S * N3, 64, (long)8 * 64 * S, (long)64 * S, 8);

  // 4-6) fused scores -> entmax -> PV
  fused_attn<<<dim3(64, 64), 256, 0, stream>>>(QKVb, Vt, attn);

  // 7) y = attn @ Wo, split-K x2 (bias folded into ln_res)
  gemm_bt<2, 2, 0, false><<<dim3(BS / 128, D / 128, 2), 256, 0, stream>>>(
      attn, Wot, nullptr, yp, D / 2, D, D, D, 0, D / 2, 0, D / 2, 0, PSTR, 2, 1.f);

  // 8) x1 = x + LN(y0+y1+bo)*g1 + be1
  ln_res<true, 2><<<BS, 256, 0, stream>>>(x, yp, PSTR, bo, g1, be1, x1, x1b);

  // 9) h = mish(x1 @ W1 + b1) (bf16)
  gemm_bt<2, 2, 2, true><<<dim3(BS / 128, F / 128, 1), 256, 0, stream>>>(
      x1b, W1t, b1, hb, D, D, D, F, 0, 0, 0, 0, 0, 0, 1, 1.f);

  // 10) y2 = h @ W2, split-K x4
  gemm_bt<2, 2, 0, false><<<dim3(BS / 128, D / 128, 4), 256, 0, stream>>>(
      hb, W2t, nullptr, yp, F / 4, F, F, D, 0, F / 4, 0, F / 4, 0, PSTR, 4, 1.f);

  // 11) out = x1 + LN(y0..y3+b2)*g2 + be2
  ln_res<false, 4><<<BS, 256, 0, stream>>>(x1, yp, PSTR, b2, g2, be2, out, nullptr);
}

// Round 7
// 393.532 us; speedup vs baseline: 1.0794x; 1.0794x over previous
//
#include <hip/hip_runtime.h>

// ---------------------------------------------------------------------------
// EncoderLayer: x -> MHA(entmax1.5) -> +LN -> FFN(mish) -> +LN
// B=8 S=1024 D=512 H=8 hd=64 F=2048.  bf16 MFMA GEMMs, fp32 accum/epilogues.
// Round 7: split attention + closed-form support-iteration entmax with the
// CORRECT stopping rule (support fixed-point, k==kprev — round-5-verified).
// s2-based early exit is invalid for this iteration (overshoot state has
// s2<1 before the support re-solve).
// ---------------------------------------------------------------------------

typedef float f32x4 __attribute__((ext_vector_type(4)));
typedef __bf16 b8 __attribute__((ext_vector_type(8)));

#define DEV static __device__ __forceinline__

DEV unsigned short f2bf(float f) {
  unsigned u = __float_as_uint(f);
  u += 0x7fffu + ((u >> 16) & 1u);   // RNE
  return (unsigned short)(u >> 16);
}
DEV float bf2f(unsigned short b) { return __uint_as_float(((unsigned)b) << 16); }

DEV float mishf(float x) {
  if (x > 20.f) return x;
  float e = __expf(x);
  float u = 1.f + e;
  u *= u;
  return x * ((u - 1.f) / (u + 1.f));
}

DEV void async16(const void* g, void* l) {
  __builtin_amdgcn_global_load_lds(
      (const __attribute__((address_space(1))) unsigned int*)g,
      (__attribute__((address_space(3))) unsigned int*)l, 16, 0, 0);
}

// ---------------------------------------------------------------------------
// Generic MFMA GEMM:  C[M,N] = alpha * A[M,K] * Bt[N,K]^T (+bias) (+mish)
// Batched / split-K via blockIdx.z: off = (z/hdiv)*s1 + (z%hdiv)*s2.
// (verified since round 2)
// ---------------------------------------------------------------------------
template <int WM, int WN, int EPI, bool OUTBF>
__global__ __launch_bounds__(256) void gemm_bt(
    const unsigned short* __restrict__ A, const unsigned short* __restrict__ Bt,
    const float* __restrict__ bias, void* __restrict__ Cp,
    int K, int lda, int ldb, int ldc,
    long sA1, long sA2, long sB1, long sB2, long sC1, long sC2,
    int hdiv, float alpha) {
  constexpr int BM = WM * 64, BN = WN * 64;
  __shared__ unsigned short smA[BM * 32];
  __shared__ unsigned short smB[BN * 32];

  const int tid = threadIdx.x;
  const int lane = tid & 63;
  const int z = blockIdx.z;
  const long zi = z / hdiv, zr = z % hdiv;
  const unsigned short* Ab = A + zi * sA1 + zr * sA2 + (long)blockIdx.x * BM * lda;
  const unsigned short* Bb = Bt + zi * sB1 + zr * sB2 + (long)blockIdx.y * BN * ldb;

  int siA[WM];
  const unsigned short* gA[WM];
#pragma unroll
  for (int q = 0; q < WM; ++q) {
    int si = q * 256 + tid;
    int m = si >> 2, s = si & 3, g = s ^ ((m >> 1) & 3);
    siA[q] = si;
    gA[q] = Ab + (long)m * lda + g * 8;
  }
  int siB[WN];
  const unsigned short* gB[WN];
#pragma unroll
  for (int q = 0; q < WN; ++q) {
    int si = q * 256 + tid;
    int m = si >> 2, s = si & 3, g = s ^ ((m >> 1) & 3);
    siB[q] = si;
    gB[q] = Bb + (long)m * ldb + g * 8;
  }

  const int w = tid >> 6;
  const int wr = w / WN, wc = w % WN;
  const int fm = lane & 15, fg = lane >> 4;

  int aOff[4], bOff[4];
#pragma unroll
  for (int i = 0; i < 4; ++i) {
    int m = wr * 64 + i * 16 + fm;
    aOff[i] = (m * 4 + (fg ^ ((m >> 1) & 3))) * 8;
    int n = wc * 64 + i * 16 + fm;
    bOff[i] = (n * 4 + (fg ^ ((n >> 1) & 3))) * 8;
  }

  f32x4 acc[4][4];
#pragma unroll
  for (int i = 0; i < 4; ++i)
#pragma unroll
    for (int j = 0; j < 4; ++j) acc[i][j] = (f32x4){0.f, 0.f, 0.f, 0.f};

  for (int k0 = 0; k0 < K; k0 += 32) {
    __syncthreads();
#pragma unroll
    for (int q = 0; q < WM; ++q) async16(gA[q] + k0, (void*)&smA[siA[q] * 8]);
#pragma unroll
    for (int q = 0; q < WN; ++q) async16(gB[q] + k0, (void*)&smB[siB[q] * 8]);
    __syncthreads();

    b8 aF[4], bF[4];
#pragma unroll
    for (int i = 0; i < 4; ++i) aF[i] = *(const b8*)&smA[aOff[i]];
#pragma unroll
    for (int j = 0; j < 4; ++j) bF[j] = *(const b8*)&smB[bOff[j]];
#pragma unroll
    for (int i = 0; i < 4; ++i)
#pragma unroll
      for (int j = 0; j < 4; ++j)
        acc[i][j] = __builtin_amdgcn_mfma_f32_16x16x32_bf16(aF[i], bF[j], acc[i][j], 0, 0, 0);
  }

  const long cbase = zi * sC1 + zr * sC2;
  const int row0 = blockIdx.x * BM + wr * 64 + fg * 4;
  const int col0 = blockIdx.y * BN + wc * 64 + fm;
#pragma unroll
  for (int i = 0; i < 4; ++i) {
#pragma unroll
    for (int j = 0; j < 4; ++j) {
      const int col = col0 + j * 16;
      float bv = (EPI >= 1) ? bias[col] : 0.f;
#pragma unroll
      for (int r = 0; r < 4; ++r) {
        const int row = row0 + i * 16 + r;
        float v = acc[i][j][r] * alpha + bv;
        if (EPI == 2) v = mishf(v);
        const long idx = cbase + (long)row * ldc + col;
        if constexpr (OUTBF)
          ((unsigned short*)Cp)[idx] = f2bf(v);
        else
          ((float*)Cp)[idx] = v;
      }
    }
  }
}

// ---------------------------------------------------------------------------
// entmax 1.5 over rows of 1024 (in-place bf16). One wave per row, register-
// resident. z already = scores/2. Closed-form support iteration: from
// tau0 = max-1 (support superset), each step solves sum_{S}(z-tau')^2 = 1
// exactly for the current support S (reference's mean - sqrt(clip(delta))).
// STOP when the support is a fixed point (k unchanged) — tau is then exact.
// k via ballot (wave-uniform). Round-5-verified numerics.
// ---------------------------------------------------------------------------
__global__ __launch_bounds__(256) void entmax_rows(unsigned short* __restrict__ P) {
  const int tid = threadIdx.x, lane = tid & 63, wv = tid >> 6;
  const long row = (long)blockIdx.x * 4 + wv;
  unsigned short* p = P + row * 1024;

  union { uint4 v; unsigned short u[8]; } a, b;
  a.v = *(const uint4*)(p + lane * 16);
  b.v = *(const uint4*)(p + lane * 16 + 8);
  float zv[16];
#pragma unroll
  for (int i = 0; i < 8; ++i) {
    zv[i] = bf2f(a.u[i]);
    zv[8 + i] = bf2f(b.u[i]);
  }

  float m = zv[0];
#pragma unroll
  for (int i = 1; i < 16; ++i) m = fmaxf(m, zv[i]);
#pragma unroll
  for (int o = 32; o; o >>= 1) m = fmaxf(m, __shfl_xor(m, o));
#pragma unroll
  for (int i = 0; i < 16; ++i) zv[i] -= m;

  float tau = -1.f;
  int kprev = -1;
  for (int it = 0; it < 12; ++it) {
    float s1 = 0.f, s2 = 0.f;
    int k = 0;
#pragma unroll
    for (int i = 0; i < 16; ++i) {
      float h = zv[i] - tau;
      k += __popcll(__ballot(h > 0.f));
      float hp = fmaxf(h, 0.f);
      s1 += hp;
      s2 = fmaf(hp, hp, s2);
    }
#pragma unroll
    for (int o = 32; o; o >>= 1) {
      s1 += __shfl_xor(s1, o);
      s2 += __shfl_xor(s2, o);
    }
    if (k == kprev) break;  // support fixed point -> tau exact (wave-uniform)
    kprev = k;
    float kf = (float)k;
    float disc = fmaxf(fmaf(s1, s1, -kf * (s2 - 1.f)), 0.f);
    tau += (s1 - __builtin_sqrtf(disc)) / kf;
  }

#pragma unroll
  for (int i = 0; i < 8; ++i) {
    float h0 = fmaxf(zv[i] - tau, 0.f);
    float h1 = fmaxf(zv[8 + i] - tau, 0.f);
    a.u[i] = f2bf(h0 * h0);
    b.u[i] = f2bf(h1 * h1);
  }
  *(uint4*)(p + lane * 16) = a.v;
  *(uint4*)(p + lane * 16 + 8) = b.v;
}

// ---------------------------------------------------------------------------
__global__ __launch_bounds__(256) void cast_f2b(const float* __restrict__ in,
                                                unsigned short* __restrict__ out, long n) {
  long i = ((long)blockIdx.x * 256 + threadIdx.x) * 4;
  if (i >= n) return;
  float4 v = *(const float4*)&in[i];
  unsigned lo = (unsigned)f2bf(v.x) | ((unsigned)f2bf(v.y) << 16);
  unsigned hi = (unsigned)f2bf(v.z) | ((unsigned)f2bf(v.w) << 16);
  uint2 p;
  p.x = lo;
  p.y = hi;
  *(uint2*)&out[i] = p;
}

__global__ __launch_bounds__(256) void concat3(const float* __restrict__ a,
                                               const float* __restrict__ b,
                                               const float* __restrict__ c,
                                               float* __restrict__ o) {
  int i = blockIdx.x * 256 + threadIdx.x;
  if (i < 512) o[i] = a[i];
  else if (i < 1024) o[i] = b[i - 512];
  else if (i < 1536) o[i] = c[i - 1024];
}

__global__ __launch_bounds__(256) void transpose_f2b(const float* __restrict__ in,
                                                     unsigned short* __restrict__ out,
                                                     int ldi, int ldo) {
  __shared__ float t[32][33];
  const int tx = threadIdx.x & 31, ty = threadIdx.x >> 5;
  const int r0 = blockIdx.y * 32, c0 = blockIdx.x * 32;
#pragma unroll
  for (int q = 0; q < 4; ++q) {
    int r = ty + q * 8;
    t[r][tx] = in[(long)(r0 + r) * ldi + c0 + tx];
  }
  __syncthreads();
#pragma unroll
  for (int q = 0; q < 4; ++q) {
    int r = ty + q * 8;
    out[(long)(c0 + r) * ldo + r0 + tx] = f2bf(t[tx][r]);
  }
}

__global__ __launch_bounds__(256) void transpose_b2b(const unsigned short* __restrict__ in,
                                                     unsigned short* __restrict__ out,
                                                     int ldi, int ldo, long i1, long i2,
                                                     long o1, long o2, int hdiv) {
  __shared__ unsigned short t[32][33];
  const int z = blockIdx.z;
  in += (long)(z / hdiv) * i1 + (long)(z % hdiv) * i2;
  out += (long)(z / hdiv) * o1 + (long)(z % hdiv) * o2;
  const int tx = threadIdx.x & 31, ty = threadIdx.x >> 5;
  const int r0 = blockIdx.y * 32, c0 = blockIdx.x * 32;
#pragma unroll
  for (int q = 0; q < 4; ++q) {
    int r = ty + q * 8;
    t[r][tx] = in[(long)(r0 + r) * ldi + c0 + tx];
  }
  __syncthreads();
#pragma unroll
  for (int q = 0; q < 4; ++q) {
    int r = ty + q * 8;
    out[(long)(c0 + r) * ldo + r0 + tx] = t[tx][r];
  }
}

// ---------------------------------------------------------------------------
// out = xin + LayerNorm(sum_j y[j*ystr] + ybias)*g + be   (row 512)
// ---------------------------------------------------------------------------
template <bool WB, int NS>
__global__ __launch_bounds__(256) void ln_res(const float* __restrict__ xin,
                                              const float* __restrict__ y, long ystr,
                                              const float* __restrict__ ybias,
                                              const float* __restrict__ g,
                                              const float* __restrict__ be,
                                              float* __restrict__ xo,
                                              unsigned short* __restrict__ xob) {
  const int row = blockIdx.x, tid = threadIdx.x, lane = tid & 63, wv = tid >> 6;
  const long base = (long)row * 512 + tid * 2;
  const int c = tid * 2;
  float2 v = *(const float2*)&y[base];
#pragma unroll
  for (int j = 1; j < NS; ++j) {
    float2 u = *(const float2*)&y[base + j * ystr];
    v.x += u.x;
    v.y += u.y;
  }
  v.x += ybias[c];
  v.y += ybias[c + 1];
  float s1 = v.x + v.y, s2 = v.x * v.x + v.y * v.y;
  for (int o = 32; o; o >>= 1) {
    s1 += __shfl_xor(s1, o);
    s2 += __shfl_xor(s2, o);
  }
  __shared__ float red[4][2];
  if (lane == 0) {
    red[wv][0] = s1;
    red[wv][1] = s2;
  }
  __syncthreads();
  s1 = red[0][0] + red[1][0] + red[2][0] + red[3][0];
  s2 = red[0][1] + red[1][1] + red[2][1] + red[3][1];
  const float mu = s1 * (1.f / 512.f);
  const float rstd = rsqrtf(s2 * (1.f / 512.f) - mu * mu + 1e-5f);
  float2 xv = *(const float2*)&xin[base];
  float o0 = xv.x + (v.x - mu) * rstd * g[c] + be[c];
  float o1 = xv.y + (v.y - mu) * rstd * g[c + 1] + be[c + 1];
  float2 ov;
  ov.x = o0;
  ov.y = o1;
  *(float2*)&xo[base] = ov;
  if constexpr (WB) {
    unsigned pk = (unsigned)f2bf(o0) | ((unsigned)f2bf(o1) << 16);
    *(unsigned*)&xob[base] = pk;
  }
}

// ---------------------------------------------------------------------------
extern "C" void kernel_launch(void* const* d_in, const int* in_sizes, int n_in,
                              void* d_out, int out_size, void* d_ws, size_t ws_size,
                              hipStream_t stream) {
  const int B = 8, S = 1024, D = 512, H = 8, F = 2048;
  const int BS = B * S;  // 8192 rows
  const int N3 = 3 * D;  // 1536

  const float* x = (const float*)d_in[0];
  const float* Wq = (const float*)d_in[1];
  const float* bq = (const float*)d_in[2];
  const float* Wk = (const float*)d_in[3];
  const float* bk = (const float*)d_in[4];
  const float* Wv = (const float*)d_in[5];
  const float* bv = (const float*)d_in[6];
  const float* Wo = (const float*)d_in[7];
  const float* bo = (const float*)d_in[8];
  const float* g1 = (const float*)d_in[9];
  const float* be1 = (const float*)d_in[10];
  const float* W1 = (const float*)d_in[11];
  const float* b1 = (const float*)d_in[12];
  const float* W2 = (const float*)d_in[13];
  const float* b2 = (const float*)d_in[14];
  const float* g2 = (const float*)d_in[15];
  const float* be2 = (const float*)d_in[16];
  float* out = (float*)d_out;

  char* w = (char*)d_ws;
  size_t off = 0;
  auto alloc = [&](size_t bytes) -> void* {
    void* p = w + off;
    off += bytes;
    off = (off + 255) & ~(size_t)255;
    return p;
  };

  unsigned short* xb = (unsigned short*)alloc((size_t)BS * D * 2);
  unsigned short* Wqkvt = (unsigned short*)alloc((size_t)N3 * D * 2);
  unsigned short* Wot = (unsigned short*)alloc((size_t)D * D * 2);
  unsigned short* W1t = (unsigned short*)alloc((size_t)F * D * 2);
  unsigned short* W2t = (unsigned short*)alloc((size_t)D * F * 2);
  float* bqkv = (float*)alloc((size_t)N3 * 4);
  unsigned short* QKVb = (unsigned short*)alloc((size_t)BS * N3 * 2);
  unsigned short* Vt = (unsigned short*)alloc((size_t)BS * D * 2);
  unsigned short* attn = (unsigned short*)alloc((size_t)BS * D * 2);
  unsigned short* P = (unsigned short*)alloc((size_t)B * H * S * S * 2);  // 128 MiB
  float* x1 = (float*)alloc((size_t)BS * D * 4);
  unsigned short* hb = (unsigned short*)alloc((size_t)BS * F * 2);
  unsigned short* x1b = xb;   // reuse: xb dead after QKV GEMM
  float* yp = (float*)P;      // reuse: P dead after PV GEMM (67 MB < 128 MB)
  const long PSTR = (long)BS * D;

  const long SS = (long)S * S;
  const long HSS = (long)H * SS;

  // 1) casts + weight transposes (bf16, N x K form)
  cast_f2b<<<(BS * D) / 1024, 256, 0, stream>>>(x, xb, (long)BS * D);
  transpose_f2b<<<dim3(16, 16, 1), 256, 0, stream>>>(Wq, Wqkvt, D, D);
  transpose_f2b<<<dim3(16, 16, 1), 256, 0, stream>>>(Wk, Wqkvt + (size_t)D * D, D, D);
  transpose_f2b<<<dim3(16, 16, 1), 256, 0, stream>>>(Wv, Wqkvt + (size_t)2 * D * D, D, D);
  transpose_f2b<<<dim3(16, 16, 1), 256, 0, stream>>>(Wo, Wot, D, D);
  transpose_f2b<<<dim3(F / 32, D / 32, 1), 256, 0, stream>>>(W1, W1t, F, D);
  transpose_f2b<<<dim3(D / 32, F / 32, 1), 256, 0, stream>>>(W2, W2t, D, F);
  concat3<<<6, 256, 0, stream>>>(bq, bk, bv, bqkv);

  // 2) merged QKV projection: [8192][1536] bf16
  gemm_bt<2, 2, 1, true><<<dim3(BS / 128, N3 / 128, 1), 256, 0, stream>>>(
      xb, Wqkvt, bqkv, QKVb, D, D, D, N3, 0, 0, 0, 0, 0, 0, 1, 1.f);

  // 3) V -> Vt[(b,h), d, s]
  transpose_b2b<<<dim3(2, 32, 64), 256, 0, stream>>>(
      QKVb + 1024, Vt, N3, S, (long)S * N3, 64, (long)8 * 64 * S, (long)64 * S, 8);

  // 4) scores z = (Q K^T)/16 -> P bf16   (Q at col 0, K at col 512 of QKVb)
  gemm_bt<2, 2, 0, true><<<dim3(S / 128, S / 128, B * H), 256, 0, stream>>>(
      QKVb, QKVb + 512, nullptr, P, 64, N3, N3, S,
      (long)S * N3, 64, (long)S * N3, 64, HSS, SS, H, 1.f / 16.f);

  // 5) entmax-1.5 per row, in place (support iteration, k-fixed-point stop)
  entmax_rows<<<(B * H * S) / 4, 256, 0, stream>>>(P);

  // 6) attn = P @ V   (256x64 tiles)
  gemm_bt<4, 1, 0, true><<<dim3(S / 256, 1, B * H), 256, 0, stream>>>(
      P, Vt, nullptr, attn, S, S, S, D,
      HSS, SS, (long)8 * 64 * S, (long)64 * S, (long)S * D, 64, H, 1.f);

  // 7) y = attn @ Wo, split-K x2 (bias folded into ln_res)
  gemm_bt<2, 2, 0, false><<<dim3(BS / 128, D / 128, 2), 256, 0, stream>>>(
      attn, Wot, nullptr, yp, D / 2, D, D, D, 0, D / 2, 0, D / 2, 0, PSTR, 2, 1.f);

  // 8) x1 = x + LN(y0+y1+bo)*g1 + be1
  ln_res<true, 2><<<BS, 256, 0, stream>>>(x, yp, PSTR, bo, g1, be1, x1, x1b);

  // 9) h = mish(x1 @ W1 + b1) (bf16)
  gemm_bt<2, 2, 2, true><<<dim3(BS / 128, F / 128, 1), 256, 0, stream>>>(
      x1b, W1t, b1, hb, D, D, D, F, 0, 0, 0, 0, 0, 0, 1, 1.f);

  // 10) y2 = h @ W2, split-K x4
  gemm_bt<2, 2, 0, false><<<dim3(BS / 128, D / 128, 4), 256, 0, stream>>>(
      hb, W2t, nullptr, yp, F / 4, F, F, D, 0, F / 4, 0, F / 4, 0, PSTR, 4, 1.f);

  // 11) out = x1 + LN(y0..y3+b2)*g2 + be2
  ln_res<false, 4><<<BS, 256, 0, stream>>>(x1, yp, PSTR, b2, g2, be2, out, nullptr);
}

// Round 8
// 376.189 us; speedup vs baseline: 1.1291x; 1.0461x over previous
//
#include <hip/hip_runtime.h>

// ---------------------------------------------------------------------------
// EncoderLayer: x -> MHA(entmax1.5) -> +LN -> FFN(mish) -> +LN
// B=8 S=1024 D=512 H=8 hd=64 F=2048.  bf16 MFMA GEMMs, fp32 accum/epilogues.
// Round 8: packed-fp32 entmax inner loop (f32x2 + elementwise builtins ->
// v_pk_add/fma), merged prep kernel (1 launch vs 9), W2 split-K x4 -> x2.
// Split attention layout (round-7-verified): scores GEMM -> entmax -> PV.
// ---------------------------------------------------------------------------

typedef float f32x4 __attribute__((ext_vector_type(4)));
typedef float f32x2 __attribute__((ext_vector_type(2)));
typedef __bf16 b8 __attribute__((ext_vector_type(8)));

#define DEV static __device__ __forceinline__

DEV unsigned short f2bf(float f) {
  unsigned u = __float_as_uint(f);
  u += 0x7fffu + ((u >> 16) & 1u);   // RNE
  return (unsigned short)(u >> 16);
}
DEV float bf2f(unsigned short b) { return __uint_as_float(((unsigned)b) << 16); }

DEV float mishf(float x) {
  if (x > 20.f) return x;
  float e = __expf(x);
  float u = 1.f + e;
  u *= u;
  return x * ((u - 1.f) / (u + 1.f));
}

DEV void async16(const void* g, void* l) {
  __builtin_amdgcn_global_load_lds(
      (const __attribute__((address_space(1))) unsigned int*)g,
      (__attribute__((address_space(3))) unsigned int*)l, 16, 0, 0);
}

// ---------------------------------------------------------------------------
// Generic MFMA GEMM:  C[M,N] = alpha * A[M,K] * Bt[N,K]^T (+bias) (+mish)
// Batched / split-K via blockIdx.z: off = (z/hdiv)*s1 + (z%hdiv)*s2.
// (verified since round 2)
// ---------------------------------------------------------------------------
template <int WM, int WN, int EPI, bool OUTBF>
__global__ __launch_bounds__(256) void gemm_bt(
    const unsigned short* __restrict__ A, const unsigned short* __restrict__ Bt,
    const float* __restrict__ bias, void* __restrict__ Cp,
    int K, int lda, int ldb, int ldc,
    long sA1, long sA2, long sB1, long sB2, long sC1, long sC2,
    int hdiv, float alpha) {
  constexpr int BM = WM * 64, BN = WN * 64;
  __shared__ unsigned short smA[BM * 32];
  __shared__ unsigned short smB[BN * 32];

  const int tid = threadIdx.x;
  const int lane = tid & 63;
  const int z = blockIdx.z;
  const long zi = z / hdiv, zr = z % hdiv;
  const unsigned short* Ab = A + zi * sA1 + zr * sA2 + (long)blockIdx.x * BM * lda;
  const unsigned short* Bb = Bt + zi * sB1 + zr * sB2 + (long)blockIdx.y * BN * ldb;

  int siA[WM];
  const unsigned short* gA[WM];
#pragma unroll
  for (int q = 0; q < WM; ++q) {
    int si = q * 256 + tid;
    int m = si >> 2, s = si & 3, g = s ^ ((m >> 1) & 3);
    siA[q] = si;
    gA[q] = Ab + (long)m * lda + g * 8;
  }
  int siB[WN];
  const unsigned short* gB[WN];
#pragma unroll
  for (int q = 0; q < WN; ++q) {
    int si = q * 256 + tid;
    int m = si >> 2, s = si & 3, g = s ^ ((m >> 1) & 3);
    siB[q] = si;
    gB[q] = Bb + (long)m * ldb + g * 8;
  }

  const int w = tid >> 6;
  const int wr = w / WN, wc = w % WN;
  const int fm = lane & 15, fg = lane >> 4;

  int aOff[4], bOff[4];
#pragma unroll
  for (int i = 0; i < 4; ++i) {
    int m = wr * 64 + i * 16 + fm;
    aOff[i] = (m * 4 + (fg ^ ((m >> 1) & 3))) * 8;
    int n = wc * 64 + i * 16 + fm;
    bOff[i] = (n * 4 + (fg ^ ((n >> 1) & 3))) * 8;
  }

  f32x4 acc[4][4];
#pragma unroll
  for (int i = 0; i < 4; ++i)
#pragma unroll
    for (int j = 0; j < 4; ++j) acc[i][j] = (f32x4){0.f, 0.f, 0.f, 0.f};

  for (int k0 = 0; k0 < K; k0 += 32) {
    __syncthreads();
#pragma unroll
    for (int q = 0; q < WM; ++q) async16(gA[q] + k0, (void*)&smA[siA[q] * 8]);
#pragma unroll
    for (int q = 0; q < WN; ++q) async16(gB[q] + k0, (void*)&smB[siB[q] * 8]);
    __syncthreads();

    b8 aF[4], bF[4];
#pragma unroll
    for (int i = 0; i < 4; ++i) aF[i] = *(const b8*)&smA[aOff[i]];
#pragma unroll
    for (int j = 0; j < 4; ++j) bF[j] = *(const b8*)&smB[bOff[j]];
#pragma unroll
    for (int i = 0; i < 4; ++i)
#pragma unroll
      for (int j = 0; j < 4; ++j)
        acc[i][j] = __builtin_amdgcn_mfma_f32_16x16x32_bf16(aF[i], bF[j], acc[i][j], 0, 0, 0);
  }

  const long cbase = zi * sC1 + zr * sC2;
  const int row0 = blockIdx.x * BM + wr * 64 + fg * 4;
  const int col0 = blockIdx.y * BN + wc * 64 + fm;
#pragma unroll
  for (int i = 0; i < 4; ++i) {
#pragma unroll
    for (int j = 0; j < 4; ++j) {
      const int col = col0 + j * 16;
      float bv = (EPI >= 1) ? bias[col] : 0.f;
#pragma unroll
      for (int r = 0; r < 4; ++r) {
        const int row = row0 + i * 16 + r;
        float v = acc[i][j][r] * alpha + bv;
        if (EPI == 2) v = mishf(v);
        const long idx = cbase + (long)row * ldc + col;
        if constexpr (OUTBF)
          ((unsigned short*)Cp)[idx] = f2bf(v);
        else
          ((float*)Cp)[idx] = v;
      }
    }
  }
}

// ---------------------------------------------------------------------------
// entmax 1.5 over rows of 1024 (in-place bf16). One wave per row. Closed-form
// support iteration (round-7-verified numerics, k-fixed-point stop). State
// held as f32x2 pairs; elementwise builtins let the backend emit packed
// v_pk_add_f32 / v_pk_fma_f32 (sub/add/fma pack; max/cmp stay scalar).
// tau0 = max-1 folded (no centering pass): h = z - tau identical either way.
// ---------------------------------------------------------------------------
__global__ __launch_bounds__(256) void entmax_rows(unsigned short* __restrict__ P) {
  const int tid = threadIdx.x, lane = tid & 63, wv = tid >> 6;
  const long row = (long)blockIdx.x * 4 + wv;
  unsigned short* p = P + row * 1024;

  union { uint4 v; unsigned short u[8]; } a, b;
  a.v = *(const uint4*)(p + lane * 16);
  b.v = *(const uint4*)(p + lane * 16 + 8);
  f32x2 zp[8];
#pragma unroll
  for (int i = 0; i < 4; ++i) {
    zp[i] = (f32x2){bf2f(a.u[2 * i]), bf2f(a.u[2 * i + 1])};
    zp[4 + i] = (f32x2){bf2f(b.u[2 * i]), bf2f(b.u[2 * i + 1])};
  }

  f32x2 mv = zp[0];
#pragma unroll
  for (int i = 1; i < 8; ++i) mv = __builtin_elementwise_max(mv, zp[i]);
  float m = fmaxf(mv.x, mv.y);
#pragma unroll
  for (int o = 32; o; o >>= 1) m = fmaxf(m, __shfl_xor(m, o));

  float tau = m - 1.f;
  int kprev = -1;
  const f32x2 zero2 = (f32x2){0.f, 0.f};
  for (int it = 0; it < 12; ++it) {
    const f32x2 t2 = (f32x2){tau, tau};
    f32x2 s1v = zero2, s2v = zero2;
    int k = 0;
#pragma unroll
    for (int i = 0; i < 8; ++i) {
      f32x2 h = zp[i] - t2;
      k += __popcll(__ballot(h.x > 0.f));
      k += __popcll(__ballot(h.y > 0.f));
      f32x2 hp = __builtin_elementwise_max(h, zero2);
      s1v += hp;
      s2v += hp * hp;  // -ffp-contract -> v_pk_fma_f32
    }
    float s1 = s1v.x + s1v.y, s2 = s2v.x + s2v.y;
#pragma unroll
    for (int o = 32; o; o >>= 1) {
      s1 += __shfl_xor(s1, o);
      s2 += __shfl_xor(s2, o);
    }
    if (k == kprev) break;  // support fixed point -> tau exact (wave-uniform)
    kprev = k;
    float kf = (float)k;
    float disc = fmaxf(fmaf(s1, s1, -kf * (s2 - 1.f)), 0.f);
    tau += (s1 - __builtin_sqrtf(disc)) / kf;
  }

  const f32x2 t2 = (f32x2){tau, tau};
#pragma unroll
  for (int i = 0; i < 4; ++i) {
    f32x2 h0 = __builtin_elementwise_max(zp[i] - t2, zero2);
    f32x2 h1 = __builtin_elementwise_max(zp[4 + i] - t2, zero2);
    f32x2 p0 = h0 * h0, p1 = h1 * h1;
    a.u[2 * i] = f2bf(p0.x);
    a.u[2 * i + 1] = f2bf(p0.y);
    b.u[2 * i] = f2bf(p1.x);
    b.u[2 * i + 1] = f2bf(p1.y);
  }
  *(uint4*)(p + lane * 16) = a.v;
  *(uint4*)(p + lane * 16 + 8) = b.v;
}

// ---------------------------------------------------------------------------
// Merged prep: x cast + 6 weight transposes + bias concat in ONE launch.
// Block ranges: [0,4096) cast x; [4096,5120) Wq/Wk/Wv/Wo 512x512 transposes;
// [5120,6144) W1 (grid 64x16); [6144,7168) W2 (grid 16x64); [7168,7174) concat.
// ---------------------------------------------------------------------------
__global__ __launch_bounds__(256) void prep_all(
    const float* __restrict__ x, unsigned short* __restrict__ xb,
    const float* __restrict__ Wq, const float* __restrict__ Wk,
    const float* __restrict__ Wv, const float* __restrict__ Wo,
    const float* __restrict__ W1, const float* __restrict__ W2,
    unsigned short* __restrict__ Wqkvt, unsigned short* __restrict__ Wot,
    unsigned short* __restrict__ W1t, unsigned short* __restrict__ W2t,
    const float* __restrict__ bq, const float* __restrict__ bk,
    const float* __restrict__ bv, float* __restrict__ bqkv) {
  __shared__ float t[32][33];
  const int bid = blockIdx.x, tid = threadIdx.x;

  if (bid < 4096) {  // cast x -> bf16, 4 elems/thread
    long i = ((long)bid * 256 + tid) * 4;
    float4 v = *(const float4*)&x[i];
    uint2 pk;
    pk.x = (unsigned)f2bf(v.x) | ((unsigned)f2bf(v.y) << 16);
    pk.y = (unsigned)f2bf(v.z) | ((unsigned)f2bf(v.w) << 16);
    *(uint2*)&xb[i] = pk;
    return;
  }

  const float* in;
  unsigned short* out;
  int ldi, ldo, bx, by;
  if (bid < 5120) {
    int t4 = (bid - 4096) >> 8, local = (bid - 4096) & 255;
    const float* ins[4] = {Wq, Wk, Wv, Wo};
    unsigned short* outs[4] = {Wqkvt, Wqkvt + 512 * 512, Wqkvt + 2 * 512 * 512, Wot};
    in = ins[t4];
    out = outs[t4];
    ldi = 512;
    ldo = 512;
    bx = local & 15;
    by = local >> 4;
  } else if (bid < 6144) {
    int local = bid - 5120;  // W1 [512][2048] -> W1t [2048][512], grid 64x16
    in = W1;
    out = W1t;
    ldi = 2048;
    ldo = 512;
    bx = local & 63;
    by = local >> 6;
  } else if (bid < 7168) {
    int local = bid - 6144;  // W2 [2048][512] -> W2t [512][2048], grid 16x64
    in = W2;
    out = W2t;
    ldi = 512;
    ldo = 2048;
    bx = local & 15;
    by = local >> 4;
  } else {  // concat biases
    int i = (bid - 7168) * 256 + tid;
    if (i < 512) bqkv[i] = bq[i];
    else if (i < 1024) bqkv[i] = bk[i - 512];
    else if (i < 1536) bqkv[i] = bv[i - 1024];
    return;
  }

  const int tx = tid & 31, ty = tid >> 5;
  const int r0 = by * 32, c0 = bx * 32;
#pragma unroll
  for (int q = 0; q < 4; ++q) {
    int r = ty + q * 8;
    t[r][tx] = in[(long)(r0 + r) * ldi + c0 + tx];
  }
  __syncthreads();
#pragma unroll
  for (int q = 0; q < 4; ++q) {
    int r = ty + q * 8;
    out[(long)(c0 + r) * ldo + r0 + tx] = f2bf(t[tx][r]);
  }
}

// bf16 batched transpose (for V -> V^T per (b,h))
__global__ __launch_bounds__(256) void transpose_b2b(const unsigned short* __restrict__ in,
                                                     unsigned short* __restrict__ out,
                                                     int ldi, int ldo, long i1, long i2,
                                                     long o1, long o2, int hdiv) {
  __shared__ unsigned short t[32][33];
  const int z = blockIdx.z;
  in += (long)(z / hdiv) * i1 + (long)(z % hdiv) * i2;
  out += (long)(z / hdiv) * o1 + (long)(z % hdiv) * o2;
  const int tx = threadIdx.x & 31, ty = threadIdx.x >> 5;
  const int r0 = blockIdx.y * 32, c0 = blockIdx.x * 32;
#pragma unroll
  for (int q = 0; q < 4; ++q) {
    int r = ty + q * 8;
    t[r][tx] = in[(long)(r0 + r) * ldi + c0 + tx];
  }
  __syncthreads();
#pragma unroll
  for (int q = 0; q < 4; ++q) {
    int r = ty + q * 8;
    out[(long)(c0 + r) * ldo + r0 + tx] = t[tx][r];
  }
}

// ---------------------------------------------------------------------------
// out = xin + LayerNorm(sum_j y[j*ystr] + ybias)*g + be   (row 512)
// ---------------------------------------------------------------------------
template <bool WB, int NS>
__global__ __launch_bounds__(256) void ln_res(const float* __restrict__ xin,
                                              const float* __restrict__ y, long ystr,
                                              const float* __restrict__ ybias,
                                              const float* __restrict__ g,
                                              const float* __restrict__ be,
                                              float* __restrict__ xo,
                                              unsigned short* __restrict__ xob) {
  const int row = blockIdx.x, tid = threadIdx.x, lane = tid & 63, wv = tid >> 6;
  const long base = (long)row * 512 + tid * 2;
  const int c = tid * 2;
  float2 v = *(const float2*)&y[base];
#pragma unroll
  for (int j = 1; j < NS; ++j) {
    float2 u = *(const float2*)&y[base + j * ystr];
    v.x += u.x;
    v.y += u.y;
  }
  v.x += ybias[c];
  v.y += ybias[c + 1];
  float s1 = v.x + v.y, s2 = v.x * v.x + v.y * v.y;
  for (int o = 32; o; o >>= 1) {
    s1 += __shfl_xor(s1, o);
    s2 += __shfl_xor(s2, o);
  }
  __shared__ float red[4][2];
  if (lane == 0) {
    red[wv][0] = s1;
    red[wv][1] = s2;
  }
  __syncthreads();
  s1 = red[0][0] + red[1][0] + red[2][0] + red[3][0];
  s2 = red[0][1] + red[1][1] + red[2][1] + red[3][1];
  const float mu = s1 * (1.f / 512.f);
  const float rstd = rsqrtf(s2 * (1.f / 512.f) - mu * mu + 1e-5f);
  float2 xv = *(const float2*)&xin[base];
  float o0 = xv.x + (v.x - mu) * rstd * g[c] + be[c];
  float o1 = xv.y + (v.y - mu) * rstd * g[c + 1] + be[c + 1];
  float2 ov;
  ov.x = o0;
  ov.y = o1;
  *(float2*)&xo[base] = ov;
  if constexpr (WB) {
    unsigned pk = (unsigned)f2bf(o0) | ((unsigned)f2bf(o1) << 16);
    *(unsigned*)&xob[base] = pk;
  }
}

// ---------------------------------------------------------------------------
extern "C" void kernel_launch(void* const* d_in, const int* in_sizes, int n_in,
                              void* d_out, int out_size, void* d_ws, size_t ws_size,
                              hipStream_t stream) {
  const int B = 8, S = 1024, D = 512, H = 8, F = 2048;
  const int BS = B * S;  // 8192 rows
  const int N3 = 3 * D;  // 1536

  const float* x = (const float*)d_in[0];
  const float* Wq = (const float*)d_in[1];
  const float* bq = (const float*)d_in[2];
  const float* Wk = (const float*)d_in[3];
  const float* bk = (const float*)d_in[4];
  const float* Wv = (const float*)d_in[5];
  const float* bv = (const float*)d_in[6];
  const float* Wo = (const float*)d_in[7];
  const float* bo = (const float*)d_in[8];
  const float* g1 = (const float*)d_in[9];
  const float* be1 = (const float*)d_in[10];
  const float* W1 = (const float*)d_in[11];
  const float* b1 = (const float*)d_in[12];
  const float* W2 = (const float*)d_in[13];
  const float* b2 = (const float*)d_in[14];
  const float* g2 = (const float*)d_in[15];
  const float* be2 = (const float*)d_in[16];
  float* out = (float*)d_out;

  char* w = (char*)d_ws;
  size_t off = 0;
  auto alloc = [&](size_t bytes) -> void* {
    void* p = w + off;
    off += bytes;
    off = (off + 255) & ~(size_t)255;
    return p;
  };

  unsigned short* xb = (unsigned short*)alloc((size_t)BS * D * 2);
  unsigned short* Wqkvt = (unsigned short*)alloc((size_t)N3 * D * 2);
  unsigned short* Wot = (unsigned short*)alloc((size_t)D * D * 2);
  unsigned short* W1t = (unsigned short*)alloc((size_t)F * D * 2);
  unsigned short* W2t = (unsigned short*)alloc((size_t)D * F * 2);
  float* bqkv = (float*)alloc((size_t)N3 * 4);
  unsigned short* QKVb = (unsigned short*)alloc((size_t)BS * N3 * 2);
  unsigned short* Vt = (unsigned short*)alloc((size_t)BS * D * 2);
  unsigned short* attn = (unsigned short*)alloc((size_t)BS * D * 2);
  unsigned short* P = (unsigned short*)alloc((size_t)B * H * S * S * 2);  // 128 MiB
  float* x1 = (float*)alloc((size_t)BS * D * 4);
  unsigned short* hb = (unsigned short*)alloc((size_t)BS * F * 2);
  unsigned short* x1b = xb;   // reuse: xb dead after QKV GEMM
  float* yp = (float*)P;      // reuse: P dead after PV GEMM
  const long PSTR = (long)BS * D;

  const long SS = (long)S * S;
  const long HSS = (long)H * SS;

  // 1) merged prep: cast x, transpose all weights, concat qkv bias
  prep_all<<<7174, 256, 0, stream>>>(x, xb, Wq, Wk, Wv, Wo, W1, W2,
                                     Wqkvt, Wot, W1t, W2t, bq, bk, bv, bqkv);

  // 2) merged QKV projection: [8192][1536] bf16
  gemm_bt<2, 2, 1, true><<<dim3(BS / 128, N3 / 128, 1), 256, 0, stream>>>(
      xb, Wqkvt, bqkv, QKVb, D, D, D, N3, 0, 0, 0, 0, 0, 0, 1, 1.f);

  // 3) V -> Vt[(b,h), d, s]
  transpose_b2b<<<dim3(2, 32, 64), 256, 0, stream>>>(
      QKVb + 1024, Vt, N3, S, (long)S * N3, 64, (long)8 * 64 * S, (long)64 * S, 8);

  // 4) scores z = (Q K^T)/16 -> P bf16   (Q at col 0, K at col 512 of QKVb)
  gemm_bt<2, 2, 0, true><<<dim3(S / 128, S / 128, B * H), 256, 0, stream>>>(
      QKVb, QKVb + 512, nullptr, P, 64, N3, N3, S,
      (long)S * N3, 64, (long)S * N3, 64, HSS, SS, H, 1.f / 16.f);

  // 5) entmax-1.5 per row, in place (support iteration, packed fp32)
  entmax_rows<<<(B * H * S) / 4, 256, 0, stream>>>(P);

  // 6) attn = P @ V   (256x64 tiles)
  gemm_bt<4, 1, 0, true><<<dim3(S / 256, 1, B * H), 256, 0, stream>>>(
      P, Vt, nullptr, attn, S, S, S, D,
      HSS, SS, (long)8 * 64 * S, (long)64 * S, (long)S * D, 64, H, 1.f);

  // 7) y = attn @ Wo, split-K x2 (bias folded into ln_res)
  gemm_bt<2, 2, 0, false><<<dim3(BS / 128, D / 128, 2), 256, 0, stream>>>(
      attn, Wot, nullptr, yp, D / 2, D, D, D, 0, D / 2, 0, D / 2, 0, PSTR, 2, 1.f);

  // 8) x1 = x + LN(y0+y1+bo)*g1 + be1
  ln_res<true, 2><<<BS, 256, 0, stream>>>(x, yp, PSTR, bo, g1, be1, x1, x1b);

  // 9) h = mish(x1 @ W1 + b1) (bf16)
  gemm_bt<2, 2, 2, true><<<dim3(BS / 128, F / 128, 1), 256, 0, stream>>>(
      x1b, W1t, b1, hb, D, D, D, F, 0, 0, 0, 0, 0, 0, 1, 1.f);

  // 10) y2 = h @ W2, split-K x2 (K-chunks of 1024)
  gemm_bt<2, 2, 0, false><<<dim3(BS / 128, D / 128, 2), 256, 0, stream>>>(
      hb, W2t, nullptr, yp, F / 2, F, F, D, 0, F / 2, 0, F / 2, 0, PSTR, 2, 1.f);

  // 11) out = x1 + LN(y0+y1+b2)*g2 + be2
  ln_res<false, 2><<<BS, 256, 0, stream>>>(x1, yp, PSTR, b2, g2, be2, out, nullptr);
}

// Round 9
// 355.014 us; speedup vs baseline: 1.1965x; 1.0596x over previous
//
#include <hip/hip_runtime.h>

// ---------------------------------------------------------------------------
// EncoderLayer: x -> MHA(entmax1.5) -> +LN -> FFN(mish) -> +LN
// B=8 S=1024 D=512 H=8 hd=64 F=2048.  bf16 MFMA GEMMs, fp32 accum/epilogues.
// Round 9: gemm_bt BK=32 -> BK=64 (half the barrier/vmcnt(0) drains per GEMM;
// the known ~20% stall of the 2-barrier K-loop structure). 8-group XOR row
// swizzle (verified in rounds 3-5 fused staging). Rest unchanged from R8.
// ---------------------------------------------------------------------------

typedef float f32x4 __attribute__((ext_vector_type(4)));
typedef float f32x2 __attribute__((ext_vector_type(2)));
typedef __bf16 b8 __attribute__((ext_vector_type(8)));

#define DEV static __device__ __forceinline__

DEV unsigned short f2bf(float f) {
  unsigned u = __float_as_uint(f);
  u += 0x7fffu + ((u >> 16) & 1u);   // RNE
  return (unsigned short)(u >> 16);
}
DEV float bf2f(unsigned short b) { return __uint_as_float(((unsigned)b) << 16); }

DEV float mishf(float x) {
  if (x > 20.f) return x;
  float e = __expf(x);
  float u = 1.f + e;
  u *= u;
  return x * ((u - 1.f) / (u + 1.f));
}

DEV void async16(const void* g, void* l) {
  __builtin_amdgcn_global_load_lds(
      (const __attribute__((address_space(1))) unsigned int*)g,
      (__attribute__((address_space(3))) unsigned int*)l, 16, 0, 0);
}

// ---------------------------------------------------------------------------
// Generic MFMA GEMM:  C[M,N] = alpha * A[M,K] * Bt[N,K]^T (+bias) (+mish)
// Batched / split-K via blockIdx.z: off = (z/hdiv)*s1 + (z%hdiv)*s2.
// BK=64: LDS row = 8 groups of 8 bf16; slot s of row m holds group s^(m&7).
// K must be a multiple of 64.
// ---------------------------------------------------------------------------
template <int WM, int WN, int EPI, bool OUTBF>
__global__ __launch_bounds__(256) void gemm_bt(
    const unsigned short* __restrict__ A, const unsigned short* __restrict__ Bt,
    const float* __restrict__ bias, void* __restrict__ Cp,
    int K, int lda, int ldb, int ldc,
    long sA1, long sA2, long sB1, long sB2, long sC1, long sC2,
    int hdiv, float alpha) {
  constexpr int BM = WM * 64, BN = WN * 64;
  constexpr int NA = WM * 2, NB = WN * 2;  // staging slots per thread
  __shared__ unsigned short smA[BM * 64];
  __shared__ unsigned short smB[BN * 64];

  const int tid = threadIdx.x;
  const int lane = tid & 63;
  const int z = blockIdx.z;
  const long zi = z / hdiv, zr = z % hdiv;
  const unsigned short* Ab = A + zi * sA1 + zr * sA2 + (long)blockIdx.x * BM * lda;
  const unsigned short* Bb = Bt + zi * sB1 + zr * sB2 + (long)blockIdx.y * BN * ldb;

  int siA[NA];
  const unsigned short* gA[NA];
#pragma unroll
  for (int q = 0; q < NA; ++q) {
    int si = q * 256 + tid;
    int m = si >> 3, s = si & 7, g = s ^ (m & 7);
    siA[q] = si;
    gA[q] = Ab + (long)m * lda + g * 8;
  }
  int siB[NB];
  const unsigned short* gB[NB];
#pragma unroll
  for (int q = 0; q < NB; ++q) {
    int si = q * 256 + tid;
    int m = si >> 3, s = si & 7, g = s ^ (m & 7);
    siB[q] = si;
    gB[q] = Bb + (long)m * ldb + g * 8;
  }

  const int w = tid >> 6;
  const int wr = w / WN, wc = w % WN;
  const int fm = lane & 15, fg = lane >> 4;

  // frag read offsets: row m, k-group kg = ks*4+fg lives in slot kg^(m&7);
  // m&7 == fm&7 for all tile rows (row base is a multiple of 16).
  int aOff[4][2], bOff[4][2];
#pragma unroll
  for (int i = 0; i < 4; ++i)
#pragma unroll
    for (int ks = 0; ks < 2; ++ks) {
      int m = wr * 64 + i * 16 + fm;
      aOff[i][ks] = (m * 8 + ((ks * 4 + fg) ^ (fm & 7))) * 8;
      int n = wc * 64 + i * 16 + fm;
      bOff[i][ks] = (n * 8 + ((ks * 4 + fg) ^ (fm & 7))) * 8;
    }

  f32x4 acc[4][4];
#pragma unroll
  for (int i = 0; i < 4; ++i)
#pragma unroll
    for (int j = 0; j < 4; ++j) acc[i][j] = (f32x4){0.f, 0.f, 0.f, 0.f};

  for (int k0 = 0; k0 < K; k0 += 64) {
    __syncthreads();
#pragma unroll
    for (int q = 0; q < NA; ++q) async16(gA[q] + k0, (void*)&smA[siA[q] * 8]);
#pragma unroll
    for (int q = 0; q < NB; ++q) async16(gB[q] + k0, (void*)&smB[siB[q] * 8]);
    __syncthreads();  // implies vmcnt(0): staging complete

#pragma unroll
    for (int ks = 0; ks < 2; ++ks) {
      b8 aF[4], bF[4];
#pragma unroll
      for (int i = 0; i < 4; ++i) aF[i] = *(const b8*)&smA[aOff[i][ks]];
#pragma unroll
      for (int j = 0; j < 4; ++j) bF[j] = *(const b8*)&smB[bOff[j][ks]];
#pragma unroll
      for (int i = 0; i < 4; ++i)
#pragma unroll
        for (int j = 0; j < 4; ++j)
          acc[i][j] = __builtin_amdgcn_mfma_f32_16x16x32_bf16(aF[i], bF[j], acc[i][j], 0, 0, 0);
    }
  }

  const long cbase = zi * sC1 + zr * sC2;
  const int row0 = blockIdx.x * BM + wr * 64 + fg * 4;
  const int col0 = blockIdx.y * BN + wc * 64 + fm;
#pragma unroll
  for (int i = 0; i < 4; ++i) {
#pragma unroll
    for (int j = 0; j < 4; ++j) {
      const int col = col0 + j * 16;
      float bv = (EPI >= 1) ? bias[col] : 0.f;
#pragma unroll
      for (int r = 0; r < 4; ++r) {
        const int row = row0 + i * 16 + r;
        float v = acc[i][j][r] * alpha + bv;
        if (EPI == 2) v = mishf(v);
        const long idx = cbase + (long)row * ldc + col;
        if constexpr (OUTBF)
          ((unsigned short*)Cp)[idx] = f2bf(v);
        else
          ((float*)Cp)[idx] = v;
      }
    }
  }
}

// ---------------------------------------------------------------------------
// entmax 1.5 over rows of 1024 (in-place bf16). One wave per row. Closed-form
// support iteration, k-fixed-point stop (round-7/8-verified).
// ---------------------------------------------------------------------------
__global__ __launch_bounds__(256) void entmax_rows(unsigned short* __restrict__ P) {
  const int tid = threadIdx.x, lane = tid & 63, wv = tid >> 6;
  const long row = (long)blockIdx.x * 4 + wv;
  unsigned short* p = P + row * 1024;

  union { uint4 v; unsigned short u[8]; } a, b;
  a.v = *(const uint4*)(p + lane * 16);
  b.v = *(const uint4*)(p + lane * 16 + 8);
  f32x2 zp[8];
#pragma unroll
  for (int i = 0; i < 4; ++i) {
    zp[i] = (f32x2){bf2f(a.u[2 * i]), bf2f(a.u[2 * i + 1])};
    zp[4 + i] = (f32x2){bf2f(b.u[2 * i]), bf2f(b.u[2 * i + 1])};
  }

  f32x2 mv = zp[0];
#pragma unroll
  for (int i = 1; i < 8; ++i) mv = __builtin_elementwise_max(mv, zp[i]);
  float m = fmaxf(mv.x, mv.y);
#pragma unroll
  for (int o = 32; o; o >>= 1) m = fmaxf(m, __shfl_xor(m, o));

  float tau = m - 1.f;
  int kprev = -1;
  const f32x2 zero2 = (f32x2){0.f, 0.f};
  for (int it = 0; it < 12; ++it) {
    const f32x2 t2 = (f32x2){tau, tau};
    f32x2 s1v = zero2, s2v = zero2;
    int k = 0;
#pragma unroll
    for (int i = 0; i < 8; ++i) {
      f32x2 h = zp[i] - t2;
      k += __popcll(__ballot(h.x > 0.f));
      k += __popcll(__ballot(h.y > 0.f));
      f32x2 hp = __builtin_elementwise_max(h, zero2);
      s1v += hp;
      s2v += hp * hp;
    }
    float s1 = s1v.x + s1v.y, s2 = s2v.x + s2v.y;
#pragma unroll
    for (int o = 32; o; o >>= 1) {
      s1 += __shfl_xor(s1, o);
      s2 += __shfl_xor(s2, o);
    }
    if (k == kprev) break;  // support fixed point -> tau exact (wave-uniform)
    kprev = k;
    float kf = (float)k;
    float disc = fmaxf(fmaf(s1, s1, -kf * (s2 - 1.f)), 0.f);
    tau += (s1 - __builtin_sqrtf(disc)) / kf;
  }

  const f32x2 t2 = (f32x2){tau, tau};
#pragma unroll
  for (int i = 0; i < 4; ++i) {
    f32x2 h0 = __builtin_elementwise_max(zp[i] - t2, zero2);
    f32x2 h1 = __builtin_elementwise_max(zp[4 + i] - t2, zero2);
    f32x2 p0 = h0 * h0, p1 = h1 * h1;
    a.u[2 * i] = f2bf(p0.x);
    a.u[2 * i + 1] = f2bf(p0.y);
    b.u[2 * i] = f2bf(p1.x);
    b.u[2 * i + 1] = f2bf(p1.y);
  }
  *(uint4*)(p + lane * 16) = a.v;
  *(uint4*)(p + lane * 16 + 8) = b.v;
}

// ---------------------------------------------------------------------------
// Merged prep: x cast + 6 weight transposes + bias concat in ONE launch.
// ---------------------------------------------------------------------------
__global__ __launch_bounds__(256) void prep_all(
    const float* __restrict__ x, unsigned short* __restrict__ xb,
    const float* __restrict__ Wq, const float* __restrict__ Wk,
    const float* __restrict__ Wv, const float* __restrict__ Wo,
    const float* __restrict__ W1, const float* __restrict__ W2,
    unsigned short* __restrict__ Wqkvt, unsigned short* __restrict__ Wot,
    unsigned short* __restrict__ W1t, unsigned short* __restrict__ W2t,
    const float* __restrict__ bq, const float* __restrict__ bk,
    const float* __restrict__ bv, float* __restrict__ bqkv) {
  __shared__ float t[32][33];
  const int bid = blockIdx.x, tid = threadIdx.x;

  if (bid < 4096) {  // cast x -> bf16, 4 elems/thread
    long i = ((long)bid * 256 + tid) * 4;
    float4 v = *(const float4*)&x[i];
    uint2 pk;
    pk.x = (unsigned)f2bf(v.x) | ((unsigned)f2bf(v.y) << 16);
    pk.y = (unsigned)f2bf(v.z) | ((unsigned)f2bf(v.w) << 16);
    *(uint2*)&xb[i] = pk;
    return;
  }

  const float* in;
  unsigned short* out;
  int ldi, ldo, bx, by;
  if (bid < 5120) {
    int t4 = (bid - 4096) >> 8, local = (bid - 4096) & 255;
    const float* ins[4] = {Wq, Wk, Wv, Wo};
    unsigned short* outs[4] = {Wqkvt, Wqkvt + 512 * 512, Wqkvt + 2 * 512 * 512, Wot};
    in = ins[t4];
    out = outs[t4];
    ldi = 512;
    ldo = 512;
    bx = local & 15;
    by = local >> 4;
  } else if (bid < 6144) {
    int local = bid - 5120;  // W1 [512][2048] -> W1t [2048][512]
    in = W1;
    out = W1t;
    ldi = 2048;
    ldo = 512;
    bx = local & 63;
    by = local >> 6;
  } else if (bid < 7168) {
    int local = bid - 6144;  // W2 [2048][512] -> W2t [512][2048]
    in = W2;
    out = W2t;
    ldi = 512;
    ldo = 2048;
    bx = local & 15;
    by = local >> 4;
  } else {  // concat biases
    int i = (bid - 7168) * 256 + tid;
    if (i < 512) bqkv[i] = bq[i];
    else if (i < 1024) bqkv[i] = bk[i - 512];
    else if (i < 1536) bqkv[i] = bv[i - 1024];
    return;
  }

  const int tx = tid & 31, ty = tid >> 5;
  const int r0 = by * 32, c0 = bx * 32;
#pragma unroll
  for (int q = 0; q < 4; ++q) {
    int r = ty + q * 8;
    t[r][tx] = in[(long)(r0 + r) * ldi + c0 + tx];
  }
  __syncthreads();
#pragma unroll
  for (int q = 0; q < 4; ++q) {
    int r = ty + q * 8;
    out[(long)(c0 + r) * ldo + r0 + tx] = f2bf(t[tx][r]);
  }
}

// bf16 batched transpose (for V -> V^T per (b,h))
__global__ __launch_bounds__(256) void transpose_b2b(const unsigned short* __restrict__ in,
                                                     unsigned short* __restrict__ out,
                                                     int ldi, int ldo, long i1, long i2,
                                                     long o1, long o2, int hdiv) {
  __shared__ unsigned short t[32][33];
  const int z = blockIdx.z;
  in += (long)(z / hdiv) * i1 + (long)(z % hdiv) * i2;
  out += (long)(z / hdiv) * o1 + (long)(z % hdiv) * o2;
  const int tx = threadIdx.x & 31, ty = threadIdx.x >> 5;
  const int r0 = blockIdx.y * 32, c0 = blockIdx.x * 32;
#pragma unroll
  for (int q = 0; q < 4; ++q) {
    int r = ty + q * 8;
    t[r][tx] = in[(long)(r0 + r) * ldi + c0 + tx];
  }
  __syncthreads();
#pragma unroll
  for (int q = 0; q < 4; ++q) {
    int r = ty + q * 8;
    out[(long)(c0 + r) * ldo + r0 + tx] = t[tx][r];
  }
}

// ---------------------------------------------------------------------------
// out = xin + LayerNorm(sum_j y[j*ystr] + ybias)*g + be   (row 512)
// ---------------------------------------------------------------------------
template <bool WB, int NS>
__global__ __launch_bounds__(256) void ln_res(const float* __restrict__ xin,
                                              const float* __restrict__ y, long ystr,
                                              const float* __restrict__ ybias,
                                              const float* __restrict__ g,
                                              const float* __restrict__ be,
                                              float* __restrict__ xo,
                                              unsigned short* __restrict__ xob) {
  const int row = blockIdx.x, tid = threadIdx.x, lane = tid & 63, wv = tid >> 6;
  const long base = (long)row * 512 + tid * 2;
  const int c = tid * 2;
  float2 v = *(const float2*)&y[base];
#pragma unroll
  for (int j = 1; j < NS; ++j) {
    float2 u = *(const float2*)&y[base + j * ystr];
    v.x += u.x;
    v.y += u.y;
  }
  v.x += ybias[c];
  v.y += ybias[c + 1];
  float s1 = v.x + v.y, s2 = v.x * v.x + v.y * v.y;
  for (int o = 32; o; o >>= 1) {
    s1 += __shfl_xor(s1, o);
    s2 += __shfl_xor(s2, o);
  }
  __shared__ float red[4][2];
  if (lane == 0) {
    red[wv][0] = s1;
    red[wv][1] = s2;
  }
  __syncthreads();
  s1 = red[0][0] + red[1][0] + red[2][0] + red[3][0];
  s2 = red[0][1] + red[1][1] + red[2][1] + red[3][1];
  const float mu = s1 * (1.f / 512.f);
  const float rstd = rsqrtf(s2 * (1.f / 512.f) - mu * mu + 1e-5f);
  float2 xv = *(const float2*)&xin[base];
  float o0 = xv.x + (v.x - mu) * rstd * g[c] + be[c];
  float o1 = xv.y + (v.y - mu) * rstd * g[c + 1] + be[c + 1];
  float2 ov;
  ov.x = o0;
  ov.y = o1;
  *(float2*)&xo[base] = ov;
  if constexpr (WB) {
    unsigned pk = (unsigned)f2bf(o0) | ((unsigned)f2bf(o1) << 16);
    *(unsigned*)&xob[base] = pk;
  }
}

// ---------------------------------------------------------------------------
extern "C" void kernel_launch(void* const* d_in, const int* in_sizes, int n_in,
                              void* d_out, int out_size, void* d_ws, size_t ws_size,
                              hipStream_t stream) {
  const int B = 8, S = 1024, D = 512, H = 8, F = 2048;
  const int BS = B * S;  // 8192 rows
  const int N3 = 3 * D;  // 1536

  const float* x = (const float*)d_in[0];
  const float* Wq = (const float*)d_in[1];
  const float* bq = (const float*)d_in[2];
  const float* Wk = (const float*)d_in[3];
  const float* bk = (const float*)d_in[4];
  const float* Wv = (const float*)d_in[5];
  const float* bv = (const float*)d_in[6];
  const float* Wo = (const float*)d_in[7];
  const float* bo = (const float*)d_in[8];
  const float* g1 = (const float*)d_in[9];
  const float* be1 = (const float*)d_in[10];
  const float* W1 = (const float*)d_in[11];
  const float* b1 = (const float*)d_in[12];
  const float* W2 = (const float*)d_in[13];
  const float* b2 = (const float*)d_in[14];
  const float* g2 = (const float*)d_in[15];
  const float* be2 = (const float*)d_in[16];
  float* out = (float*)d_out;

  char* w = (char*)d_ws;
  size_t off = 0;
  auto alloc = [&](size_t bytes) -> void* {
    void* p = w + off;
    off += bytes;
    off = (off + 255) & ~(size_t)255;
    return p;
  };

  unsigned short* xb = (unsigned short*)alloc((size_t)BS * D * 2);
  unsigned short* Wqkvt = (unsigned short*)alloc((size_t)N3 * D * 2);
  unsigned short* Wot = (unsigned short*)alloc((size_t)D * D * 2);
  unsigned short* W1t = (unsigned short*)alloc((size_t)F * D * 2);
  unsigned short* W2t = (unsigned short*)alloc((size_t)D * F * 2);
  float* bqkv = (float*)alloc((size_t)N3 * 4);
  unsigned short* QKVb = (unsigned short*)alloc((size_t)BS * N3 * 2);
  unsigned short* Vt = (unsigned short*)alloc((size_t)BS * D * 2);
  unsigned short* attn = (unsigned short*)alloc((size_t)BS * D * 2);
  unsigned short* P = (unsigned short*)alloc((size_t)B * H * S * S * 2);  // 128 MiB
  float* x1 = (float*)alloc((size_t)BS * D * 4);
  unsigned short* hb = (unsigned short*)alloc((size_t)BS * F * 2);
  unsigned short* x1b = xb;   // reuse: xb dead after QKV GEMM
  float* yp = (float*)P;      // reuse: P dead after PV GEMM
  const long PSTR = (long)BS * D;

  const long SS = (long)S * S;
  const long HSS = (long)H * SS;

  // 1) merged prep: cast x, transpose all weights, concat qkv bias
  prep_all<<<7174, 256, 0, stream>>>(x, xb, Wq, Wk, Wv, Wo, W1, W2,
                                     Wqkvt, Wot, W1t, W2t, bq, bk, bv, bqkv);

  // 2) merged QKV projection: [8192][1536] bf16
  gemm_bt<2, 2, 1, true><<<dim3(BS / 128, N3 / 128, 1), 256, 0, stream>>>(
      xb, Wqkvt, bqkv, QKVb, D, D, D, N3, 0, 0, 0, 0, 0, 0, 1, 1.f);

  // 3) V -> Vt[(b,h), d, s]
  transpose_b2b<<<dim3(2, 32, 64), 256, 0, stream>>>(
      QKVb + 1024, Vt, N3, S, (long)S * N3, 64, (long)8 * 64 * S, (long)64 * S, 8);

  // 4) scores z = (Q K^T)/16 -> P bf16   (Q at col 0, K at col 512 of QKVb)
  gemm_bt<2, 2, 0, true><<<dim3(S / 128, S / 128, B * H), 256, 0, stream>>>(
      QKVb, QKVb + 512, nullptr, P, 64, N3, N3, S,
      (long)S * N3, 64, (long)S * N3, 64, HSS, SS, H, 1.f / 16.f);

  // 5) entmax-1.5 per row, in place (support iteration, packed fp32)
  entmax_rows<<<(B * H * S) / 4, 256, 0, stream>>>(P);

  // 6) attn = P @ V   (256x64 tiles)
  gemm_bt<4, 1, 0, true><<<dim3(S / 256, 1, B * H), 256, 0, stream>>>(
      P, Vt, nullptr, attn, S, S, S, D,
      HSS, SS, (long)8 * 64 * S, (long)64 * S, (long)S * D, 64, H, 1.f);

  // 7) y = attn @ Wo, split-K x2 (bias folded into ln_res)
  gemm_bt<2, 2, 0, false><<<dim3(BS / 128, D / 128, 2), 256, 0, stream>>>(
      attn, Wot, nullptr, yp, D / 2, D, D, D, 0, D / 2, 0, D / 2, 0, PSTR, 2, 1.f);

  // 8) x1 = x + LN(y0+y1+bo)*g1 + be1
  ln_res<true, 2><<<BS, 256, 0, stream>>>(x, yp, PSTR, bo, g1, be1, x1, x1b);

  // 9) h = mish(x1 @ W1 + b1) (bf16)
  gemm_bt<2, 2, 2, true><<<dim3(BS / 128, F / 128, 1), 256, 0, stream>>>(
      x1b, W1t, b1, hb, D, D, D, F, 0, 0, 0, 0, 0, 0, 1, 1.f);

  // 10) y2 = h @ W2, split-K x2 (K-chunks of 1024)
  gemm_bt<2, 2, 0, false><<<dim3(BS / 128, D / 128, 2), 256, 0, stream>>>(
      hb, W2t, nullptr, yp, F / 2, F, F, D, 0, F / 2, 0, F / 2, 0, PSTR, 2, 1.f);

  // 11) out = x1 + LN(y0+y1+b2)*g2 + be2
  ln_res<false, 2><<<BS, 256, 0, stream>>>(x1, yp, PSTR, b2, g2, be2, out, nullptr);
}